// Round 17
// baseline (228.309 us; speedup 1.0000x reference)
//
#include <hip/hip_runtime.h>
#include <hip/hip_bf16.h>
#include <stdint.h>

// B=16, TH=TS=HS=WS=1024
// res[b,i,o] = sum_j softmax_j(hp[b,i,:].sp[b,j,:]) * hp[b,j,o]
// hp = h*Wh^T + bh ; sp = s*Ws^T + bs
// R17 = R16 with G1/G2 back to fp16-A gl2lds (non-RSA, 593 TF vs RSA 478)
// plus XCD-pinned producer->consumer L2 locality:
//   cvt_pin writes h16 rows so XCD r owns rows [2048r,2048r+2048);
//   G1/G2 blocks remapped so XCD r reads exactly those panels (L2-warm);
//   order cvt_h -> G1 -> cvt_s -> G2; softmax rows pinned to G3/G4's XCD.

typedef _Float16 half_t;
typedef __attribute__((ext_vector_type(8))) _Float16 half8;   // 4 VGPR
typedef __attribute__((ext_vector_type(4))) _Float16 half4;
typedef __attribute__((ext_vector_type(4))) float floatx4;

__device__ __forceinline__ void gl2lds16(const void* g, void* l) {
    __builtin_amdgcn_global_load_lds(
        (const __attribute__((address_space(1))) uint32_t*)(uintptr_t)g,
        (__attribute__((address_space(3))) uint32_t*)(uintptr_t)l,
        16, 0, 0);
}

#define NT16 16   // K = 1024, BK = 64

// C[r][c] = sum_k A[r][k]*B[c][k] (+bias[c]); operands K-major (B^T GEMM).
// 256x256 tile, 8 waves (2Mx4N), per-wave 128x64, double-buffered 128KB LDS.
// Swizzle: rows are 128B (=32 banks); XOR byte bits 4-6 with row&7.
// SWZ: grid (4,4,16); batch remapped so a batch's 16 tiles share one XCD.
// PIN: grid (64,4); row-panels remapped so XCD r reads A rows [2048r..+2048)
//      (matches cvt_pin's writer XCD -> L2-warm staging).
template<int WF32, int WH16, int WH16T, int SWZ, int PIN>
__global__ __launch_bounds__(512, 2) void gemm256(
    const half_t* __restrict__ A, const half_t* __restrict__ B,
    const float* __restrict__ bias,
    float* __restrict__ Cf, half_t* __restrict__ Ch, half_t* __restrict__ ChT,
    int lda, int ldb, int N,
    long aBatch, long bBatch, long cfBatch, int ldcf)
{
    extern __shared__ char smem[];   // [2][ A:32KB | B:32KB ] = 128KB

    const int tid  = threadIdx.x;
    const int wave = tid >> 6;
    const int lane = tid & 63;
    const int wr = wave >> 2;        // 0..1 -> rows wr*128..+127
    const int wc = wave & 3;         // 0..3 -> cols wc*64..+63
    const int lr = lane & 15, lg = lane >> 4;

    long batch; int row0, col0;
    if constexpr (SWZ) {
        const int lin = blockIdx.x + (blockIdx.y << 2) + (blockIdx.z << 4);
        const int xcd = lin & 7, per = lin >> 3;          // 32 blocks per XCD
        batch = (xcd << 1) | (per >> 4);                  // 2 batches per XCD
        const int wt = per & 15;
        row0 = (wt & 3) * 256;
        col0 = (wt >> 2) * 256;
    } else if constexpr (PIN) {
        const int lin = blockIdx.x + (blockIdx.y << 6);   // gridDim.x == 64
        const int q = lin >> 3;
        batch = 0;
        row0 = (8 * (lin & 7) + (q & 7)) * 256;           // XCD lin&7 owns its rows
        col0 = (q >> 3) * 256;
    } else {
        batch = blockIdx.z;
        row0 = blockIdx.x * 256;
        col0 = blockIdx.y * 256;
    }

    const half_t* Ab = A + batch * aBatch;
    const half_t* Bb = B + batch * bBatch;

    floatx4 acc[8][4];
#pragma unroll
    for (int m = 0; m < 8; ++m)
#pragma unroll
        for (int n = 0; n < 4; ++n)
            acc[m][n] = (floatx4){0.f, 0.f, 0.f, 0.f};

    // hoisted stage source offsets (pre-swizzled global src for gl2lds):
    long aOff[2][2], bOff[2][2];
#pragma unroll
    for (int hh = 0; hh < 2; ++hh)
#pragma unroll
        for (int i = 0; i < 2; ++i) {
            const int off = hh * 16384 + i * 8192 + tid * 16;
            const int e = off ^ (((off >> 7) & 7) << 4);
            const int r = e >> 7, cb = e & 127;
            aOff[hh][i] = (long)(row0 + r) * (long)(lda * 2) + cb;
            bOff[hh][i] = (long)(col0 + r) * (long)(ldb * 2) + cb;
        }

    const int wave_s = __builtin_amdgcn_readfirstlane(wave);
    auto stage = [&](int buf, int kk) {
#pragma unroll
        for (int hh = 0; hh < 2; ++hh)
#pragma unroll
            for (int i = 0; i < 2; ++i)
                gl2lds16((const char*)Ab + aOff[hh][i] + (long)kk * 2,
                         smem + buf * 65536 + hh * 16384 + i * 8192 + wave_s * 1024);
#pragma unroll
        for (int hh = 0; hh < 2; ++hh)
#pragma unroll
            for (int i = 0; i < 2; ++i)
                gl2lds16((const char*)Bb + bOff[hh][i] + (long)kk * 2,
                         smem + buf * 65536 + 32768 + hh * 16384 + i * 8192 + wave_s * 1024);
    };

    // fragment-read bases (swizzle folded)
    uint32_t aof0 = (uint32_t)((wr * 128 + lr) * 128 + ((lg * 16) ^ ((lr & 7) << 4)));
    uint32_t aof1 = (uint32_t)((wr * 128 + lr) * 128 + ((64 + lg * 16) ^ ((lr & 7) << 4)));
    uint32_t bof0 = (uint32_t)(32768 + (wc * 64 + lr) * 128 + ((lg * 16) ^ ((lr & 7) << 4)));
    uint32_t bof1 = (uint32_t)(32768 + (wc * 64 + lr) * 128 + ((64 + lg * 16) ^ ((lr & 7) << 4)));

    stage(0, 0);
    __syncthreads();

    for (int t = 0; t < NT16; ++t) {
        if (t + 1 < NT16) stage((t & 1) ^ 1, (t + 1) * 64);   // T3: stage first

        half8 aF[4][2], bF[4][2];
#pragma unroll
        for (int ni = 0; ni < 4; ++ni) {
            bF[ni][0] = *(const half8*)(smem + bof0 + ni * 2048);
            bF[ni][1] = *(const half8*)(smem + bof1 + ni * 2048);
        }
#pragma unroll
        for (int mi = 0; mi < 4; ++mi) {
            aF[mi][0] = *(const half8*)(smem + aof0 + mi * 2048);
            aF[mi][1] = *(const half8*)(smem + aof1 + mi * 2048);
        }
#pragma unroll
        for (int mi = 0; mi < 4; ++mi)
#pragma unroll
            for (int ni = 0; ni < 4; ++ni)
#pragma unroll
                for (int ks = 0; ks < 2; ++ks)
                    acc[mi][ni] = __builtin_amdgcn_mfma_f32_16x16x32_f16(
                        aF[mi][ks], bF[ni][ks], acc[mi][ni], 0, 0, 0);
#pragma unroll
        for (int mi = 0; mi < 4; ++mi) {
            aF[mi][0] = *(const half8*)(smem + aof0 + (4 + mi) * 2048);
            aF[mi][1] = *(const half8*)(smem + aof1 + (4 + mi) * 2048);
        }
#pragma unroll
        for (int mi = 0; mi < 4; ++mi)
#pragma unroll
            for (int ni = 0; ni < 4; ++ni)
#pragma unroll
                for (int ks = 0; ks < 2; ++ks)
                    acc[4 + mi][ni] = __builtin_amdgcn_mfma_f32_16x16x32_f16(
                        aF[mi][ks], bF[ni][ks], acc[4 + mi][ni], 0, 0, 0);

        __syncthreads();
        aof0 ^= 65536; aof1 ^= 65536; bof0 ^= 65536; bof1 ^= 65536;
    }

    // ---- epilogue: transpose acc through LDS for coalesced 16B stores.
    {
        float* wlds = (float*)(smem + wave * 2304);   // per-wave 16x36 f32
        float bv[4];
#pragma unroll
        for (int n = 0; n < 4; ++n)
            bv[n] = bias ? bias[col0 + wc * 64 + n * 16 + lr] : 0.f;
        const int er = lane >> 2, ec = lane & 3;
        const int oc = lane >> 1, tc = lane & 1;
#pragma unroll
        for (int m = 0; m < 8; ++m) {
#pragma unroll
            for (int np = 0; np < 2; ++np) {
#pragma unroll
                for (int n2 = 0; n2 < 2; ++n2)
#pragma unroll
                    for (int j = 0; j < 4; ++j)
                        wlds[(lg * 4 + j) * 36 + n2 * 16 + lr] =
                            acc[m][np * 2 + n2][j] + bv[np * 2 + n2];
                const int grow = row0 + wr * 128 + m * 16;
                const int gcol = col0 + wc * 64 + np * 32;
                float4 q0 = *(float4*)&wlds[er * 36 + ec * 8];
                float4 q1 = *(float4*)&wlds[er * 36 + ec * 8 + 4];
                if (WF32) {
                    float* p = Cf + batch * cfBatch + (long)(grow + er) * ldcf + gcol + ec * 8;
                    *(float4*)p = q0;
                    *(float4*)(p + 4) = q1;
                }
                if (WH16) {
                    half8 o = { (half_t)q0.x, (half_t)q0.y, (half_t)q0.z, (half_t)q0.w,
                                (half_t)q1.x, (half_t)q1.y, (half_t)q1.z, (half_t)q1.w };
                    *(half8*)&Ch[batch * cfBatch + (long)(grow + er) * N + gcol + ec * 8] = o;
                }
                if (WH16T) {
                    float tv[8];
#pragma unroll
                    for (int k = 0; k < 8; ++k)
                        tv[k] = wlds[(tc * 8 + k) * 36 + oc];
                    half8 o = { (half_t)tv[0], (half_t)tv[1], (half_t)tv[2], (half_t)tv[3],
                                (half_t)tv[4], (half_t)tv[5], (half_t)tv[6], (half_t)tv[7] };
                    const int gt = grow + tc * 8;
                    *(half8*)&ChT[(long)(gt >> 10) * 1048576
                                  + (long)(gcol + oc) * 1024 + (gt & 1023)] = o;
                }
                __builtin_amdgcn_s_waitcnt(0);   // drain before next overwrite of wlds
            }
        }
    }
}

// In-place fp16 softmax, rows XCD-pinned: block l -> row 2048*(l&7)+(l>>3)
// (reads sc16 L2-hot from G3's batch pinning; leaves probs warm for G4).
__global__ void softmax_h(half_t* __restrict__ S) {
    const long l = blockIdx.x;
    const long r = 2048 * (l & 7) + (l >> 3);
    half_t* row = S + r * 1024;
    const int tid = threadIdx.x;
    const int wave = tid >> 6, lane = tid & 63;

    half4 h4 = ((const half4*)row)[tid];
    float v0 = (float)h4[0], v1 = (float)h4[1], v2 = (float)h4[2], v3 = (float)h4[3];
    float mx = fmaxf(fmaxf(v0, v1), fmaxf(v2, v3));
#pragma unroll
    for (int off = 32; off > 0; off >>= 1)
        mx = fmaxf(mx, __shfl_xor(mx, off));
    __shared__ float rmx[4], rsm[4];
    if (lane == 0) rmx[wave] = mx;
    __syncthreads();
    mx = fmaxf(fmaxf(rmx[0], rmx[1]), fmaxf(rmx[2], rmx[3]));

    float e0 = __expf(v0 - mx), e1 = __expf(v1 - mx);
    float e2 = __expf(v2 - mx), e3 = __expf(v3 - mx);
    float s = e0 + e1 + e2 + e3;
#pragma unroll
    for (int off = 32; off > 0; off >>= 1)
        s += __shfl_xor(s, off);
    if (lane == 0) rsm[wave] = s;
    __syncthreads();
    s = rsm[0] + rsm[1] + rsm[2] + rsm[3];

    const float inv = 1.0f / s;
    half4 o = { (half_t)(e0 * inv), (half_t)(e1 * inv), (half_t)(e2 * inv), (half_t)(e3 * inv) };
    ((half4*)row)[tid] = o;
}

// f32 -> fp16 cvt, XCD-pinned rows: block l handles 8 rows starting at
// 2048*(l&7) + 8*(l>>3)  (XCD r cvts rows [2048r, 2048r+2048) -> its L2).
__global__ void cvt_pin(const float4* __restrict__ src, half4* __restrict__ dst) {
    const int l = blockIdx.x;                       // 2048 blocks
    const long base = (2048L * (l & 7) + 8L * (l >> 3)) * 256;  // float4 units
    const int tid = threadIdx.x;                    // 256 threads
#pragma unroll
    for (int k = 0; k < 8; ++k) {
        float4 v = src[base + k * 256 + tid];
        half4 o = { (half_t)v.x, (half_t)v.y, (half_t)v.z, (half_t)v.w };
        dst[base + k * 256 + tid] = o;
    }
}

__global__ void cvt_f16(const float4* __restrict__ src, half4* __restrict__ dst, int n4) {
    const int stride = gridDim.x * blockDim.x;
    for (int i = blockIdx.x * blockDim.x + threadIdx.x; i < n4; i += stride) {
        float4 v = src[i];
        half4 o = { (half_t)v.x, (half_t)v.y, (half_t)v.z, (half_t)v.w };
        dst[i] = o;
    }
}

extern "C" void kernel_launch(void* const* d_in, const int* in_sizes, int n_in,
                              void* d_out, int out_size, void* d_ws, size_t ws_size,
                              hipStream_t stream) {
    const float* h  = (const float*)d_in[0];
    const float* s  = (const float*)d_in[1];
    const float* Wh = (const float*)d_in[2];
    const float* bh = (const float*)d_in[3];
    const float* Ws = (const float*)d_in[4];
    const float* bs = (const float*)d_in[5];

    const long MB = 16384;   // B*TH
    const long D  = 1024;

    // workspace carve (~196 MB)
    char* w = (char*)d_ws;
    half_t* sc16 = (half_t*)w;  w += MB * D * 2;   // 32MB fp16 scores/probs
    half_t* Wh16 = (half_t*)w;  w += D * D * 2;
    half_t* Ws16 = (half_t*)w;  w += D * D * 2;
    half_t* h16  = (half_t*)w;  w += MB * D * 2;
    half_t* s16  = (half_t*)w;  w += MB * D * 2;
    half_t* hp16 = (half_t*)w;  w += MB * D * 2;
    half_t* sp16 = (half_t*)w;  w += MB * D * 2;
    half_t* hpT  = (half_t*)w;  w += MB * D * 2;   // [16][o][t]

    (void)hipFuncSetAttribute(reinterpret_cast<const void*>(&gemm256<0,1,1,0,1>),
                        hipFuncAttributeMaxDynamicSharedMemorySize, 131072);
    (void)hipFuncSetAttribute(reinterpret_cast<const void*>(&gemm256<0,1,0,0,1>),
                        hipFuncAttributeMaxDynamicSharedMemorySize, 131072);
    (void)hipFuncSetAttribute(reinterpret_cast<const void*>(&gemm256<0,1,0,1,0>),
                        hipFuncAttributeMaxDynamicSharedMemorySize, 131072);
    (void)hipFuncSetAttribute(reinterpret_cast<const void*>(&gemm256<1,0,0,1,0>),
                        hipFuncAttributeMaxDynamicSharedMemorySize, 131072);

    cvt_f16<<<512, 256, 0, stream>>>((const float4*)Wh, (half4*)Wh16, (int)(D * D / 4));
    cvt_f16<<<512, 256, 0, stream>>>((const float4*)Ws, (half4*)Ws16, (int)(D * D / 4));

    // cvt h (XCD-pinned) then G1 immediately (reads h16 L2-warm, PIN remap)
    cvt_pin<<<2048, 256, 0, stream>>>((const float4*)h, (half4*)h16);
    gemm256<0,1,1,0,1><<<dim3(64, 4, 1), 512, 131072, stream>>>(
        h16, Wh16, bh, nullptr, hp16, hpT, 1024, 1024, 1024, 0, 0, 0, 0);

    // cvt s then G2 (same pinning)
    cvt_pin<<<2048, 256, 0, stream>>>((const float4*)s, (half4*)s16);
    gemm256<0,1,0,0,1><<<dim3(64, 4, 1), 512, 131072, stream>>>(
        s16, Ws16, bs, nullptr, sp16, nullptr, 1024, 1024, 1024, 0, 0, 0, 0);

    // GEMM3: scores[b] = hp_b * sp_b^T -> fp16, XCD-batch swizzle
    gemm256<0,1,0,1,0><<<dim3(4, 4, 16), 512, 131072, stream>>>(
        hp16, sp16, nullptr, nullptr, sc16, nullptr, 1024, 1024, 1024,
        1048576L, 1048576L, 1048576L, 0);
    // softmax over j, fp16 in place, rows XCD-pinned
    softmax_h<<<16384, 256, 0, stream>>>(sc16);
    // GEMM4: out[b] = probs_b * hpT_b^T (f32 -> d_out), XCD-batch swizzle
    gemm256<1,0,0,1,0><<<dim3(4, 4, 16), 512, 131072, stream>>>(
        sc16, hpT, nullptr, (float*)d_out, nullptr, nullptr,
        1024, 1024, 1024, 1048576L, 1048576L, 1048576L, 1024);
}

// Round 18
// 225.176 us; speedup vs baseline: 1.0139x; 1.0139x over previous
//
#include <hip/hip_runtime.h>
#include <hip/hip_bf16.h>
#include <stdint.h>

// B=16, TH=TS=HS=WS=1024
// res[b,i,o] = sum_j softmax_j(hp[b,i,:].sp[b,j,:]) * hp[b,j,o]
// hp = h*Wh^T + bh ; sp = s*Ws^T + bs
// R18 = R17 front half (cvt_pin -> PIN'd G1/G2: XCD-local L2 reuse, 49-55us
// per GEMM) + R16 back half (plain softmax order). Weight cvts merged into
// one dispatch. fp16 everywhere, f32 MFMA accum, fp16 scores.

typedef _Float16 half_t;
typedef __attribute__((ext_vector_type(8))) _Float16 half8;   // 4 VGPR
typedef __attribute__((ext_vector_type(4))) _Float16 half4;
typedef __attribute__((ext_vector_type(4))) float floatx4;

__device__ __forceinline__ void gl2lds16(const void* g, void* l) {
    __builtin_amdgcn_global_load_lds(
        (const __attribute__((address_space(1))) uint32_t*)(uintptr_t)g,
        (__attribute__((address_space(3))) uint32_t*)(uintptr_t)l,
        16, 0, 0);
}

#define NT16 16   // K = 1024, BK = 64

// C[r][c] = sum_k A[r][k]*B[c][k] (+bias[c]); operands K-major (B^T GEMM).
// 256x256 tile, 8 waves (2Mx4N), per-wave 128x64, double-buffered 128KB LDS.
// Swizzle: rows are 128B (=32 banks); XOR byte bits 4-6 with row&7.
// SWZ: grid (4,4,16); batch remapped so a batch's 16 tiles share one XCD.
// PIN: grid (64,4); row-panels remapped so XCD r reads A rows [2048r..+2048)
//      (matches cvt_pin's writer XCD -> L2-warm staging).
template<int WF32, int WH16, int WH16T, int SWZ, int PIN>
__global__ __launch_bounds__(512, 2) void gemm256(
    const half_t* __restrict__ A, const half_t* __restrict__ B,
    const float* __restrict__ bias,
    float* __restrict__ Cf, half_t* __restrict__ Ch, half_t* __restrict__ ChT,
    int lda, int ldb, int N,
    long aBatch, long bBatch, long cfBatch, int ldcf)
{
    extern __shared__ char smem[];   // [2][ A:32KB | B:32KB ] = 128KB

    const int tid  = threadIdx.x;
    const int wave = tid >> 6;
    const int lane = tid & 63;
    const int wr = wave >> 2;        // 0..1 -> rows wr*128..+127
    const int wc = wave & 3;         // 0..3 -> cols wc*64..+63
    const int lr = lane & 15, lg = lane >> 4;

    long batch; int row0, col0;
    if constexpr (SWZ) {
        const int lin = blockIdx.x + (blockIdx.y << 2) + (blockIdx.z << 4);
        const int xcd = lin & 7, per = lin >> 3;          // 32 blocks per XCD
        batch = (xcd << 1) | (per >> 4);                  // 2 batches per XCD
        const int wt = per & 15;
        row0 = (wt & 3) * 256;
        col0 = (wt >> 2) * 256;
    } else if constexpr (PIN) {
        const int lin = blockIdx.x + (blockIdx.y << 6);   // gridDim.x == 64
        const int q = lin >> 3;
        batch = 0;
        row0 = (8 * (lin & 7) + (q & 7)) * 256;           // XCD lin&7 owns its rows
        col0 = (q >> 3) * 256;
    } else {
        batch = blockIdx.z;
        row0 = blockIdx.x * 256;
        col0 = blockIdx.y * 256;
    }

    const half_t* Ab = A + batch * aBatch;
    const half_t* Bb = B + batch * bBatch;

    floatx4 acc[8][4];
#pragma unroll
    for (int m = 0; m < 8; ++m)
#pragma unroll
        for (int n = 0; n < 4; ++n)
            acc[m][n] = (floatx4){0.f, 0.f, 0.f, 0.f};

    // hoisted stage source offsets (pre-swizzled global src for gl2lds):
    long aOff[2][2], bOff[2][2];
#pragma unroll
    for (int hh = 0; hh < 2; ++hh)
#pragma unroll
        for (int i = 0; i < 2; ++i) {
            const int off = hh * 16384 + i * 8192 + tid * 16;
            const int e = off ^ (((off >> 7) & 7) << 4);
            const int r = e >> 7, cb = e & 127;
            aOff[hh][i] = (long)(row0 + r) * (long)(lda * 2) + cb;
            bOff[hh][i] = (long)(col0 + r) * (long)(ldb * 2) + cb;
        }

    const int wave_s = __builtin_amdgcn_readfirstlane(wave);
    auto stage = [&](int buf, int kk) {
#pragma unroll
        for (int hh = 0; hh < 2; ++hh)
#pragma unroll
            for (int i = 0; i < 2; ++i)
                gl2lds16((const char*)Ab + aOff[hh][i] + (long)kk * 2,
                         smem + buf * 65536 + hh * 16384 + i * 8192 + wave_s * 1024);
#pragma unroll
        for (int hh = 0; hh < 2; ++hh)
#pragma unroll
            for (int i = 0; i < 2; ++i)
                gl2lds16((const char*)Bb + bOff[hh][i] + (long)kk * 2,
                         smem + buf * 65536 + 32768 + hh * 16384 + i * 8192 + wave_s * 1024);
    };

    // fragment-read bases (swizzle folded)
    uint32_t aof0 = (uint32_t)((wr * 128 + lr) * 128 + ((lg * 16) ^ ((lr & 7) << 4)));
    uint32_t aof1 = (uint32_t)((wr * 128 + lr) * 128 + ((64 + lg * 16) ^ ((lr & 7) << 4)));
    uint32_t bof0 = (uint32_t)(32768 + (wc * 64 + lr) * 128 + ((lg * 16) ^ ((lr & 7) << 4)));
    uint32_t bof1 = (uint32_t)(32768 + (wc * 64 + lr) * 128 + ((64 + lg * 16) ^ ((lr & 7) << 4)));

    stage(0, 0);
    __syncthreads();

    for (int t = 0; t < NT16; ++t) {
        if (t + 1 < NT16) stage((t & 1) ^ 1, (t + 1) * 64);   // T3: stage first

        half8 aF[4][2], bF[4][2];
#pragma unroll
        for (int ni = 0; ni < 4; ++ni) {
            bF[ni][0] = *(const half8*)(smem + bof0 + ni * 2048);
            bF[ni][1] = *(const half8*)(smem + bof1 + ni * 2048);
        }
#pragma unroll
        for (int mi = 0; mi < 4; ++mi) {
            aF[mi][0] = *(const half8*)(smem + aof0 + mi * 2048);
            aF[mi][1] = *(const half8*)(smem + aof1 + mi * 2048);
        }
#pragma unroll
        for (int mi = 0; mi < 4; ++mi)
#pragma unroll
            for (int ni = 0; ni < 4; ++ni)
#pragma unroll
                for (int ks = 0; ks < 2; ++ks)
                    acc[mi][ni] = __builtin_amdgcn_mfma_f32_16x16x32_f16(
                        aF[mi][ks], bF[ni][ks], acc[mi][ni], 0, 0, 0);
#pragma unroll
        for (int mi = 0; mi < 4; ++mi) {
            aF[mi][0] = *(const half8*)(smem + aof0 + (4 + mi) * 2048);
            aF[mi][1] = *(const half8*)(smem + aof1 + (4 + mi) * 2048);
        }
#pragma unroll
        for (int mi = 0; mi < 4; ++mi)
#pragma unroll
            for (int ni = 0; ni < 4; ++ni)
#pragma unroll
                for (int ks = 0; ks < 2; ++ks)
                    acc[4 + mi][ni] = __builtin_amdgcn_mfma_f32_16x16x32_f16(
                        aF[mi][ks], bF[ni][ks], acc[4 + mi][ni], 0, 0, 0);

        __syncthreads();
        aof0 ^= 65536; aof1 ^= 65536; bof0 ^= 65536; bof1 ^= 65536;
    }

    // ---- epilogue: transpose acc through LDS for coalesced 16B stores.
    {
        float* wlds = (float*)(smem + wave * 2304);   // per-wave 16x36 f32
        float bv[4];
#pragma unroll
        for (int n = 0; n < 4; ++n)
            bv[n] = bias ? bias[col0 + wc * 64 + n * 16 + lr] : 0.f;
        const int er = lane >> 2, ec = lane & 3;
        const int oc = lane >> 1, tc = lane & 1;
#pragma unroll
        for (int m = 0; m < 8; ++m) {
#pragma unroll
            for (int np = 0; np < 2; ++np) {
#pragma unroll
                for (int n2 = 0; n2 < 2; ++n2)
#pragma unroll
                    for (int j = 0; j < 4; ++j)
                        wlds[(lg * 4 + j) * 36 + n2 * 16 + lr] =
                            acc[m][np * 2 + n2][j] + bv[np * 2 + n2];
                const int grow = row0 + wr * 128 + m * 16;
                const int gcol = col0 + wc * 64 + np * 32;
                float4 q0 = *(float4*)&wlds[er * 36 + ec * 8];
                float4 q1 = *(float4*)&wlds[er * 36 + ec * 8 + 4];
                if (WF32) {
                    float* p = Cf + batch * cfBatch + (long)(grow + er) * ldcf + gcol + ec * 8;
                    *(float4*)p = q0;
                    *(float4*)(p + 4) = q1;
                }
                if (WH16) {
                    half8 o = { (half_t)q0.x, (half_t)q0.y, (half_t)q0.z, (half_t)q0.w,
                                (half_t)q1.x, (half_t)q1.y, (half_t)q1.z, (half_t)q1.w };
                    *(half8*)&Ch[batch * cfBatch + (long)(grow + er) * N + gcol + ec * 8] = o;
                }
                if (WH16T) {
                    float tv[8];
#pragma unroll
                    for (int k = 0; k < 8; ++k)
                        tv[k] = wlds[(tc * 8 + k) * 36 + oc];
                    half8 o = { (half_t)tv[0], (half_t)tv[1], (half_t)tv[2], (half_t)tv[3],
                                (half_t)tv[4], (half_t)tv[5], (half_t)tv[6], (half_t)tv[7] };
                    const int gt = grow + tc * 8;
                    *(half8*)&ChT[(long)(gt >> 10) * 1048576
                                  + (long)(gcol + oc) * 1024 + (gt & 1023)] = o;
                }
                __builtin_amdgcn_s_waitcnt(0);   // drain before next overwrite of wlds
            }
        }
    }
}

// In-place fp16 softmax, plain row order (R16 back half).
__global__ void softmax_h(half_t* __restrict__ S) {
    const long r = blockIdx.x;
    half_t* row = S + r * 1024;
    const int tid = threadIdx.x;
    const int wave = tid >> 6, lane = tid & 63;

    half4 h4 = ((const half4*)row)[tid];
    float v0 = (float)h4[0], v1 = (float)h4[1], v2 = (float)h4[2], v3 = (float)h4[3];
    float mx = fmaxf(fmaxf(v0, v1), fmaxf(v2, v3));
#pragma unroll
    for (int off = 32; off > 0; off >>= 1)
        mx = fmaxf(mx, __shfl_xor(mx, off));
    __shared__ float rmx[4], rsm[4];
    if (lane == 0) rmx[wave] = mx;
    __syncthreads();
    mx = fmaxf(fmaxf(rmx[0], rmx[1]), fmaxf(rmx[2], rmx[3]));

    float e0 = __expf(v0 - mx), e1 = __expf(v1 - mx);
    float e2 = __expf(v2 - mx), e3 = __expf(v3 - mx);
    float s = e0 + e1 + e2 + e3;
#pragma unroll
    for (int off = 32; off > 0; off >>= 1)
        s += __shfl_xor(s, off);
    if (lane == 0) rsm[wave] = s;
    __syncthreads();
    s = rsm[0] + rsm[1] + rsm[2] + rsm[3];

    const float inv = 1.0f / s;
    half4 o = { (half_t)(e0 * inv), (half_t)(e1 * inv), (half_t)(e2 * inv), (half_t)(e3 * inv) };
    ((half4*)row)[tid] = o;
}

// f32 -> fp16 cvt, XCD-pinned rows: block l handles 8 rows starting at
// 2048*(l&7) + 8*(l>>3)  (XCD r cvts rows [2048r, 2048r+2048) -> its L2).
__global__ void cvt_pin(const float4* __restrict__ src, half4* __restrict__ dst) {
    const int l = blockIdx.x;                       // 2048 blocks
    const long base = (2048L * (l & 7) + 8L * (l >> 3)) * 256;  // float4 units
    const int tid = threadIdx.x;                    // 256 threads
#pragma unroll
    for (int k = 0; k < 8; ++k) {
        float4 v = src[base + k * 256 + tid];
        half4 o = { (half_t)v.x, (half_t)v.y, (half_t)v.z, (half_t)v.w };
        dst[base + k * 256 + tid] = o;
    }
}

// both weight matrices in one dispatch (1024 blocks x 256 thr, 1 float4 each x2)
__global__ void cvt_w2(const float4* __restrict__ w1, half4* __restrict__ d1,
                       const float4* __restrict__ w2, half4* __restrict__ d2) {
    const int i = blockIdx.x * 256 + threadIdx.x;   // 262144 float4s per matrix
    const float4 a = w1[i];
    d1[i] = (half4){ (half_t)a.x, (half_t)a.y, (half_t)a.z, (half_t)a.w };
    const float4 b = w2[i];
    d2[i] = (half4){ (half_t)b.x, (half_t)b.y, (half_t)b.z, (half_t)b.w };
}

extern "C" void kernel_launch(void* const* d_in, const int* in_sizes, int n_in,
                              void* d_out, int out_size, void* d_ws, size_t ws_size,
                              hipStream_t stream) {
    const float* h  = (const float*)d_in[0];
    const float* s  = (const float*)d_in[1];
    const float* Wh = (const float*)d_in[2];
    const float* bh = (const float*)d_in[3];
    const float* Ws = (const float*)d_in[4];
    const float* bs = (const float*)d_in[5];

    const long MB = 16384;   // B*TH
    const long D  = 1024;

    // workspace carve (~196 MB)
    char* w = (char*)d_ws;
    half_t* sc16 = (half_t*)w;  w += MB * D * 2;   // 32MB fp16 scores/probs
    half_t* Wh16 = (half_t*)w;  w += D * D * 2;
    half_t* Ws16 = (half_t*)w;  w += D * D * 2;
    half_t* h16  = (half_t*)w;  w += MB * D * 2;
    half_t* s16  = (half_t*)w;  w += MB * D * 2;
    half_t* hp16 = (half_t*)w;  w += MB * D * 2;
    half_t* sp16 = (half_t*)w;  w += MB * D * 2;
    half_t* hpT  = (half_t*)w;  w += MB * D * 2;   // [16][o][t]

    (void)hipFuncSetAttribute(reinterpret_cast<const void*>(&gemm256<0,1,1,0,1>),
                        hipFuncAttributeMaxDynamicSharedMemorySize, 131072);
    (void)hipFuncSetAttribute(reinterpret_cast<const void*>(&gemm256<0,1,0,0,1>),
                        hipFuncAttributeMaxDynamicSharedMemorySize, 131072);
    (void)hipFuncSetAttribute(reinterpret_cast<const void*>(&gemm256<0,1,0,1,0>),
                        hipFuncAttributeMaxDynamicSharedMemorySize, 131072);
    (void)hipFuncSetAttribute(reinterpret_cast<const void*>(&gemm256<1,0,0,1,0>),
                        hipFuncAttributeMaxDynamicSharedMemorySize, 131072);

    cvt_w2<<<1024, 256, 0, stream>>>((const float4*)Wh, (half4*)Wh16,
                                     (const float4*)Ws, (half4*)Ws16);

    // cvt h (XCD-pinned) then G1 immediately (reads h16 L2-warm, PIN remap)
    cvt_pin<<<2048, 256, 0, stream>>>((const float4*)h, (half4*)h16);
    gemm256<0,1,1,0,1><<<dim3(64, 4, 1), 512, 131072, stream>>>(
        h16, Wh16, bh, nullptr, hp16, hpT, 1024, 1024, 1024, 0, 0, 0, 0);

    // cvt s then G2 (same pinning)
    cvt_pin<<<2048, 256, 0, stream>>>((const float4*)s, (half4*)s16);
    gemm256<0,1,0,0,1><<<dim3(64, 4, 1), 512, 131072, stream>>>(
        s16, Ws16, bs, nullptr, sp16, nullptr, 1024, 1024, 1024, 0, 0, 0, 0);

    // GEMM3: scores[b] = hp_b * sp_b^T -> fp16, XCD-batch swizzle
    gemm256<0,1,0,1,0><<<dim3(4, 4, 16), 512, 131072, stream>>>(
        hp16, sp16, nullptr, nullptr, sc16, nullptr, 1024, 1024, 1024,
        1048576L, 1048576L, 1048576L, 0);
    // softmax over j, fp16 in place (plain order)
    softmax_h<<<16384, 256, 0, stream>>>(sc16);
    // GEMM4: out[b] = probs_b * hpT_b^T (f32 -> d_out), XCD-batch swizzle
    gemm256<1,0,0,1,0><<<dim3(4, 4, 16), 512, 131072, stream>>>(
        sc16, hpT, nullptr, (float*)d_out, nullptr, nullptr,
        1024, 1024, 1024, 1048576L, 1048576L, 1048576L, 1024);
}